// Round 5
// baseline (23052.699 us; speedup 1.0000x reference)
//
#include <hip/hip_runtime.h>
#include <hip/hip_bf16.h>
#include <math.h>

// EquiformerV2 block, fp32. Round 5: attn with fused so2*val weights, 2-edge
// pipelining, transposed wigner layouts, register-tiled 8-col GEMM items.
// E=40000 edges, N=2000 nodes, C=64, L2=25, M2=19, NL=2.

#define NRBF 600
#define DIN 728
#define GPTS 288
#define MAXE 160

__constant__ int d_mg[19] = {0,1,0,1,2,1,0,1,2,2,1,0,1,2,2,1,0,1,2};
__constant__ int d_loc[25] = {0,1,1,1,2,2,2,2,2,3,3,3,3,3,3,3,4,4,4,4,4,4,4,4,4};
// 4 balanced row-groups (one per wave): rows, weight-group, count {5,4,4,6}
__constant__ int d_g4m[4][6] = {{0,2,6,11,16,0},{1,3,5,7,0,0},{10,12,15,17,0,0},{4,8,9,13,14,18}};
__constant__ int d_g4w[4] = {0,1,1,2};

__device__ inline float silu_f(float v){ return v/(1.0f+__expf(-v)); }

__device__ inline void atomicMaxF(float* addr, float val){
  int* ia=(int*)addr;
  int old=*ia;
  while (__int_as_float(old) < val){
    int assumed=old;
    old = atomicCAS(ia, assumed, __float_as_int(val));
    if (old == assumed) break;
  }
}

// ---------------- CSR build ----------------
__global__ __launch_bounds__(256) void zero_cnt_kernel(int* cnt, int N){
  int i = blockIdx.x*256+threadIdx.x;
  if (i<N) cnt[i]=0;
}
__global__ __launch_bounds__(256) void csr_count_kernel(const int* __restrict__ rcv, int* cnt, int E){
  int i = blockIdx.x*256+threadIdx.x;
  if (i<E) atomicAdd(&cnt[rcv[i]],1);
}
__global__ __launch_bounds__(256) void csr_scan_kernel(const int* __restrict__ cnt,
    int* rowptr, int* fill, int N){
  __shared__ int s_part[256];
  int tid=threadIdx.x;
  int chunk=(N+255)/256;
  int lvals[12];
  int base=tid*chunk;
  int lsum=0;
  for (int i=0;i<chunk && i<12;i++){
    int v=(base+i<N)?cnt[base+i]:0;
    lvals[i]=lsum; lsum+=v;
  }
  s_part[tid]=lsum;
  __syncthreads();
  if (tid==0){
    int run=0;
    for (int t=0;t<256;t++){ int v=s_part[t]; s_part[t]=run; run+=v; }
  }
  __syncthreads();
  int off=s_part[tid];
  for (int i=0;i<chunk && i<12;i++){
    if (base+i<N){ rowptr[base+i]=off+lvals[i]; fill[base+i]=off+lvals[i]; }
  }
  if (tid==255) rowptr[N]=off+lsum;
}
__global__ __launch_bounds__(256) void csr_fill_kernel(const int* __restrict__ rcv,
    int* fill, int* eix, int E){
  int i = blockIdx.x*256+threadIdx.x;
  if (i<E){ int p=atomicAdd(&fill[rcv[i]],1); eix[p]=i; }
}

// ---------------- fused so2W @ valW prep: wsv[i][g] = [128][128] ----------------
__global__ __launch_bounds__(256) void wsv_kernel(const float* __restrict__ so2W,
    const float* __restrict__ valW, float* __restrict__ wsv){
  int i=blockIdx.x/3, g=blockIdx.x%3;
  const float* A = so2W + (size_t)i*24576 + g*8192;   // [128][64]
  const float* B = valW + (size_t)i*24576 + g*8192;   // [64][128]
  float* C = wsv + (size_t)blockIdx.x*16384;          // [128][128]
  __shared__ float sB[8192];
  for (int j=threadIdx.x;j<2048;j+=256) ((float4*)sB)[j]=((const float4*)B)[j];
  __syncthreads();
  for (int idx=threadIdx.x; idx<16384; idx+=256){
    int k=idx>>7, j=idx&127;
    float acc=0;
    #pragma unroll 4
    for (int o=0;o<64;o++) acc += A[k*64+o]*sB[o*128+j];
    C[idx]=acc;
  }
}

// ---------------- edge degree embedding, gather form (per node) ----------------
__global__ __launch_bounds__(256) void deg_gather_kernel(const float* __restrict__ ev,
    const float* __restrict__ ese, const int* __restrict__ nsp, const float* __restrict__ spe,
    const float* __restrict__ W1, const float* __restrict__ b1,
    const float* __restrict__ W2, const float* __restrict__ b2,
    const float* __restrict__ winv, const int* __restrict__ snd,
    const int* __restrict__ rowptr, const int* __restrict__ eix,
    float* __restrict__ x, int N){
  int n = blockIdx.x, tid = threadIdx.x;
  __shared__ float s_ee[4][DIN];
  __shared__ float s_h1[4][128];
  __shared__ float s_h2[4][1216];
  __shared__ float s_part[256][4];
  __shared__ float s_acc[1600];
  __shared__ float s_winv[475];
  __shared__ int s_eix[MAXE];
  __shared__ float s_d[4]; __shared__ int s_ss[4]; __shared__ int s_rs[4];
  int row0=rowptr[n];
  int cnt=rowptr[n+1]-row0; if (cnt>MAXE) cnt=MAXE;
  {
    float4 z={0,0,0,0};
    for (int j=tid;j<400;j+=256) ((float4*)s_acc)[j]=z;
    for (int j=tid;j<cnt;j+=256) s_eix[j]=eix[row0+j];
  }
  __syncthreads();
  int nq=(cnt+3)>>2;
  for (int q=0;q<nq;q++){
    int qb=q*4;
    int ne=cnt-qb; if (ne>4) ne=4;
    if (tid<4){
      int le=qb+tid;
      if (le<cnt){
        int e=s_eix[le];
        float vx=ev[3*e], vy=ev[3*e+1], vz=ev[3*e+2];
        s_d[tid]=sqrtf(vx*vx+vy*vy+vz*vz+1e-12f);
        s_ss[tid]=nsp[snd[e]];
        s_rs[tid]=nsp[n];
      } else { s_d[tid]=0.0f; s_ss[tid]=0; s_rs[tid]=0; }
    }
    __syncthreads();
    const float step = 5.0f/599.0f;
    const float inv_std = 1.0f/(2.0f*step);
    for (int j=tid;j<4*DIN;j+=256){
      int le=j/DIN, jj=j%DIN;
      float v;
      if (jj<NRBF){ float t=(s_d[le]-jj*step)*inv_std; v=__expf(-0.5f*t*t); }
      else if (jj<NRBF+64) v=ese[s_ss[le]*128+(jj-NRBF)];
      else v=ese[s_rs[le]*128+64+(jj-NRBF-64)];
      s_ee[le][jj]=v;
    }
    __syncthreads();
    {
      int o=tid&127, half=tid>>7, i0=half*364;
      float a0=0,a1=0,a2=0,a3=0;
      for (int i=i0;i<i0+364;i++){
        float w=W1[i*128+o];
        a0+=s_ee[0][i]*w; a1+=s_ee[1][i]*w; a2+=s_ee[2][i]*w; a3+=s_ee[3][i]*w;
      }
      s_part[tid][0]=a0; s_part[tid][1]=a1; s_part[tid][2]=a2; s_part[tid][3]=a3;
    }
    __syncthreads();
    if (tid<128){
      float bb=b1[tid];
      #pragma unroll
      for (int le=0;le<4;le++){
        float a=s_part[tid][le]+s_part[tid+128][le]+bb;
        s_h1[le][tid]=silu_f(a);
      }
    }
    __syncthreads();
    for (int m=tid;m<1216;m+=256){
      float bb=b2[m];
      float a0=bb,a1=bb,a2=bb,a3=bb;
      for (int o=0;o<128;o++){
        float w=W2[o*1216+m];
        a0+=s_h1[0][o]*w; a1+=s_h1[1][o]*w; a2+=s_h1[2][o]*w; a3+=s_h1[3][o]*w;
      }
      s_h2[0][m]=a0; s_h2[1][m]=a1; s_h2[2][m]=a2; s_h2[3][m]=a3;
    }
    __syncthreads();
    for (int le2=0;le2<ne;le2++){
      int e=s_eix[qb+le2];
      for (int j=tid;j<475;j+=256) s_winv[j]=winv[(size_t)e*475+j];
      __syncthreads();
      const float4* H2=(const float4*)s_h2[le2];
      for (int sI=tid;sI<400;sI+=256){
        int l=sI>>4, c4=sI&15;
        const float* wr=s_winv+l*19;
        float4 acc={0,0,0,0};
        #pragma unroll
        for (int m=0;m<19;m++){
          float w=wr[m];
          float4 hv=H2[m*16+c4];
          acc.x+=w*hv.x; acc.y+=w*hv.y; acc.z+=w*hv.z; acc.w+=w*hv.w;
        }
        float4* A=(float4*)s_acc;
        float4 cur=A[sI];
        cur.x+=acc.x; cur.y+=acc.y; cur.z+=acc.z; cur.w+=acc.w;
        A[sI]=cur;
      }
      __syncthreads();
    }
  }
  int sp=nsp[n];
  for (int j=tid;j<1600;j+=256){
    int l=j>>6, c=j&63;
    float base=(l==0)?spe[sp*64+c]:0.0f;
    x[(size_t)n*1600+j]=base+0.05f*s_acc[j];
  }
}

// ---------------- per-degree RMS norm ----------------
__global__ __launch_bounds__(256) void rmsnorm_kernel(const float* __restrict__ x,
    const float* __restrict__ w, float* __restrict__ xn, int N){
  int n = blockIdx.x, tid = threadIdx.x;
  __shared__ float s_x[1600];
  __shared__ float s_part[256];
  __shared__ float s_ms[64];
  const float* xr = x + (size_t)n*1600;
  for (int j=tid;j<1600;j+=256) s_x[j]=xr[j];
  __syncthreads();
  {
    int c = tid&63, seg = tid>>6;
    float acc=0;
    for (int l=seg;l<25;l+=4){ float v=s_x[l*64+c]; acc+=v*v; }
    s_part[tid]=acc;
  }
  __syncthreads();
  if (tid<64){
    float m=(s_part[tid]+s_part[tid+64]+s_part[tid+128]+s_part[tid+192])*(1.0f/25.0f);
    s_ms[tid]=rsqrtf(m+1e-6f);
  }
  __syncthreads();
  float* xo = xn + (size_t)n*1600;
  for (int j=tid;j<1600;j+=256){
    int l=j>>6, c=j&63;
    xo[j]=s_x[j]*s_ms[c]*w[d_loc[l]*64+c];
  }
}

__global__ __launch_bounds__(256) void init_mxden_kernel(float* mx, float* den, int N){
  int idx = blockIdx.x*256+threadIdx.x;
  if (idx < N*8){ mx[idx]=-3.0e38f; den[idx]=0.0f; }
}

// ---------------- radial MLP (edge-parallel, 4 edges/block) ----------------
__global__ __launch_bounds__(256) void rad_kernel(const float* __restrict__ ev,
    const float* __restrict__ ese, const int* __restrict__ nsp,
    const float* __restrict__ W1, const float* __restrict__ b1,
    const float* __restrict__ W2, const float* __restrict__ b2,
    const int* __restrict__ snd, const int* __restrict__ rcv,
    float* __restrict__ radb, int E){
  int e0 = blockIdx.x*4, tid = threadIdx.x;
  __shared__ float s_ee[4][DIN];
  __shared__ float s_h1[4][128];
  __shared__ float s_part[256][4];
  __shared__ float s_d[4]; __shared__ int s_ss[4]; __shared__ int s_rs[4];
  int ne = E - e0; if (ne > 4) ne = 4;
  if (tid<4){
    int e=e0+tid;
    if (e<E){
      float vx=ev[3*e], vy=ev[3*e+1], vz=ev[3*e+2];
      s_d[tid]=sqrtf(vx*vx+vy*vy+vz*vz+1e-12f);
      s_ss[tid]=nsp[snd[e]]; s_rs[tid]=nsp[rcv[e]];
    } else { s_d[tid]=0.0f; s_ss[tid]=0; s_rs[tid]=0; }
  }
  __syncthreads();
  const float step = 5.0f/599.0f;
  const float inv_std = 1.0f/(2.0f*step);
  for (int j=tid;j<4*DIN;j+=256){
    int le=j/DIN, jj=j%DIN;
    float v;
    if (jj<NRBF){ float t=(s_d[le]-jj*step)*inv_std; v=__expf(-0.5f*t*t); }
    else if (jj<NRBF+64) v=ese[s_ss[le]*128+(jj-NRBF)];
    else v=ese[s_rs[le]*128+64+(jj-NRBF-64)];
    s_ee[le][jj]=v;
  }
  __syncthreads();
  {
    int o=tid&127, half=tid>>7, i0=half*364;
    float a0=0,a1=0,a2=0,a3=0;
    for (int i=i0;i<i0+364;i++){
      float w=W1[i*128+o];
      a0+=s_ee[0][i]*w; a1+=s_ee[1][i]*w; a2+=s_ee[2][i]*w; a3+=s_ee[3][i]*w;
    }
    s_part[tid][0]=a0; s_part[tid][1]=a1; s_part[tid][2]=a2; s_part[tid][3]=a3;
  }
  __syncthreads();
  if (tid<128){
    float bb=b1[tid];
    #pragma unroll
    for (int le=0;le<4;le++){
      float a=s_part[tid][le]+s_part[tid+128][le]+bb;
      s_h1[le][tid]=silu_f(a);
    }
  }
  __syncthreads();
  for (int m=tid;m<384;m+=256){
    float bb=b2[m];
    float a0=bb,a1=bb,a2=bb,a3=bb;
    for (int o=0;o<128;o++){
      float w=W2[o*384+m];
      a0+=s_h1[0][o]*w; a1+=s_h1[1][o]*w; a2+=s_h1[2][o]*w; a3+=s_h1[3][o]*w;
    }
    if (0<ne) radb[(size_t)(e0+0)*384+m]=a0;
    if (1<ne) radb[(size_t)(e0+1)*384+m]=a1;
    if (2<ne) radb[(size_t)(e0+2)*384+m]=a2;
    if (3<ne) radb[(size_t)(e0+3)*384+m]=a3;
  }
}

// ---------------- pass 1: m=0 path -> alpha logits ----------------
__global__ __launch_bounds__(256) void logits_kernel(const float* __restrict__ xn,
    const float* __restrict__ wig, const float* __restrict__ radb,
    const float* __restrict__ so2W, const float* __restrict__ alphaW, const float* __restrict__ alphaV,
    const int* __restrict__ snd, const int* __restrict__ rcv,
    float* __restrict__ logits, float* __restrict__ mx, int E){
  int e = blockIdx.x, tid = threadIdx.x;
  __shared__ float s_cat[3200];
  __shared__ float s_wig0[25];
  __shared__ float s_msg0[128];
  __shared__ float s_sh0[64];
  __shared__ float s_a[256];
  int s = snd[e], r = rcv[e];
  const float4* xs4 = (const float4*)(xn + (size_t)s*1600);
  const float4* xr4 = (const float4*)(xn + (size_t)r*1600);
  float4* cat4 = (float4*)s_cat;
  for (int j=tid;j<400;j+=256){
    int l=j>>4, c4=j&15;
    cat4[l*32+c4]    = xs4[j];
    cat4[l*32+16+c4] = xr4[j];
  }
  if (tid<25) s_wig0[tid]=wig[(size_t)e*475+tid];
  __syncthreads();
  if (tid<128){
    float acc=0;
    #pragma unroll
    for (int l=0;l<25;l++) acc += s_wig0[l]*s_cat[l*128+tid];
    s_msg0[tid]=acc*radb[(size_t)e*384+tid];
  }
  __syncthreads();
  if (tid<64){
    float acc=0;
    #pragma unroll
    for (int k=0;k<128;k++) acc += s_msg0[k]*so2W[k*64+tid];
    s_sh0[tid]=silu_f(acc);
  }
  __syncthreads();
  {
    float acc=0;
    #pragma unroll
    for (int o=0;o<64;o++) acc += s_sh0[o]*alphaW[o*256+tid];
    s_a[tid]=silu_f(acc)*alphaV[tid];
  }
  __syncthreads();
  if (tid<8){
    float lg=0;
    #pragma unroll
    for (int q=0;q<32;q++) lg += s_a[tid*32+q];
    logits[(size_t)e*8+tid]=lg;
    atomicMaxF(&mx[r*8+tid], lg);
  }
}

__global__ __launch_bounds__(256) void den_kernel(const float* __restrict__ logits,
    const float* __restrict__ mx, const int* __restrict__ rcv,
    float* __restrict__ den, int E){
  int idx = blockIdx.x*256+threadIdx.x;
  if (idx >= E*8) return;
  int e = idx>>3, hd = idx&7, r = rcv[e];
  atomicAdd(&den[r*8+hd], __expf(logits[idx]-mx[r*8+hd]));
}

// ---------------- templated GEMM bodies (rows in registers) ----------------
template<int NR>
__device__ inline void vv_body(const int* __restrict__ rows, const float4* __restrict__ M,
    const float4* __restrict__ W, int c8, float a, float4* __restrict__ racc){
  int ca=2*c8, cb=2*c8+1;
  #pragma unroll
  for (int ri=0;ri<2*NR;ri++) racc[ri]=make_float4(0.f,0.f,0.f,0.f);
  for (int k4=0;k4<32;k4++){
    float4 w0a=W[(k4*4+0)*32+ca], w0b=W[(k4*4+0)*32+cb];
    float4 w1a=W[(k4*4+1)*32+ca], w1b=W[(k4*4+1)*32+cb];
    float4 w2a=W[(k4*4+2)*32+ca], w2b=W[(k4*4+2)*32+cb];
    float4 w3a=W[(k4*4+3)*32+ca], w3b=W[(k4*4+3)*32+cb];
    #pragma unroll
    for (int ri=0;ri<NR;ri++){
      float4 av=M[rows[ri]*32+k4];
      racc[2*ri].x += av.x*w0a.x+av.y*w1a.x+av.z*w2a.x+av.w*w3a.x;
      racc[2*ri].y += av.x*w0a.y+av.y*w1a.y+av.z*w2a.y+av.w*w3a.y;
      racc[2*ri].z += av.x*w0a.z+av.y*w1a.z+av.z*w2a.z+av.w*w3a.z;
      racc[2*ri].w += av.x*w0a.w+av.y*w1a.w+av.z*w2a.w+av.w*w3a.w;
      racc[2*ri+1].x += av.x*w0b.x+av.y*w1b.x+av.z*w2b.x+av.w*w3b.x;
      racc[2*ri+1].y += av.x*w0b.y+av.y*w1b.y+av.z*w2b.y+av.w*w3b.y;
      racc[2*ri+1].z += av.x*w0b.z+av.y*w1b.z+av.z*w2b.z+av.w*w3b.z;
      racc[2*ri+1].w += av.x*w0b.w+av.y*w1b.w+av.z*w2b.w+av.w*w3b.w;
    }
  }
  #pragma unroll
  for (int ri=0;ri<2*NR;ri++){ racc[ri].x*=a; racc[ri].y*=a; racc[ri].z*=a; racc[ri].w*=a; }
}

template<int NR>
__device__ inline void vv_write(const int* __restrict__ rows, float4* __restrict__ MV,
    int c8, const float4* __restrict__ racc){
  #pragma unroll
  for (int ri=0;ri<NR;ri++){
    MV[rows[ri]*32+2*c8]  =racc[2*ri];
    MV[rows[ri]*32+2*c8+1]=racc[2*ri+1];
  }
}

template<int NR>
__device__ inline void proj_body(const int* __restrict__ rows, const float4* __restrict__ V,
    const float4* __restrict__ P, int c8, float4* __restrict__ OE){
  int ca=2*c8, cb=2*c8+1;
  float4 racc[2*NR];
  #pragma unroll
  for (int ri=0;ri<2*NR;ri++) racc[ri]=make_float4(0.f,0.f,0.f,0.f);
  for (int k4=0;k4<32;k4++){
    float4 w0a=P[(k4*4+0)*16+ca], w0b=P[(k4*4+0)*16+cb];
    float4 w1a=P[(k4*4+1)*16+ca], w1b=P[(k4*4+1)*16+cb];
    float4 w2a=P[(k4*4+2)*16+ca], w2b=P[(k4*4+2)*16+cb];
    float4 w3a=P[(k4*4+3)*16+ca], w3b=P[(k4*4+3)*16+cb];
    #pragma unroll
    for (int ri=0;ri<NR;ri++){
      float4 av=V[rows[ri]*32+k4];
      racc[2*ri].x += av.x*w0a.x+av.y*w1a.x+av.z*w2a.x+av.w*w3a.x;
      racc[2*ri].y += av.x*w0a.y+av.y*w1a.y+av.z*w2a.y+av.w*w3a.y;
      racc[2*ri].z += av.x*w0a.z+av.y*w1a.z+av.z*w2a.z+av.w*w3a.z;
      racc[2*ri].w += av.x*w0a.w+av.y*w1a.w+av.z*w2a.w+av.w*w3a.w;
      racc[2*ri+1].x += av.x*w0b.x+av.y*w1b.x+av.z*w2b.x+av.w*w3b.x;
      racc[2*ri+1].y += av.x*w0b.y+av.y*w1b.y+av.z*w2b.y+av.w*w3b.y;
      racc[2*ri+1].z += av.x*w0b.z+av.y*w1b.z+av.z*w2b.z+av.w*w3b.z;
      racc[2*ri+1].w += av.x*w0b.w+av.y*w1b.w+av.z*w2b.w+av.w*w3b.w;
    }
  }
  #pragma unroll
  for (int ri=0;ri<NR;ri++){
    OE[rows[ri]*16+ca]=racc[2*ri];
    OE[rows[ri]*16+cb]=racc[2*ri+1];
  }
}

// ---------------- pass 2, gather: per node, 2 edges in flight ----------------
__global__ __launch_bounds__(256) void attn_gather_kernel(const float* __restrict__ xn,
    const float* __restrict__ wig, const float* __restrict__ winv, const float* __restrict__ radb,
    const float* __restrict__ wsv, const float* __restrict__ projW,
    const float* __restrict__ logits, const float* __restrict__ mx, const float* __restrict__ den,
    const int* __restrict__ snd, const int* __restrict__ rowptr, const int* __restrict__ eix,
    float* __restrict__ x, int N){
  int n=blockIdx.x, tid=threadIdx.x;
  __shared__ float s_recv[1600];    // [25][64]
  __shared__ float s_snd[2][1600];  // [25][64] per edge
  __shared__ float s_rotT[2][532];  // wigT[25][20] then winvT[19][28]
  __shared__ float s_rad[2][384];
  __shared__ float s_mv[2][2432];   // msg then vv [19][128]
  __shared__ float s_oe[2][1216];   // [19][64]
  __shared__ float s_acc[1600];
  __shared__ float s_attn[2][8];
  __shared__ int s_eix[MAXE];
  int row0=rowptr[n];
  int cnt=rowptr[n+1]-row0; if(cnt>MAXE) cnt=MAXE;
  {
    const float4* xr4=(const float4*)(xn+(size_t)n*1600);
    float4 z=make_float4(0.f,0.f,0.f,0.f);
    for (int j=tid;j<400;j+=256){ ((float4*)s_recv)[j]=xr4[j]; ((float4*)s_acc)[j]=z; }
    for (int j=tid;j<cnt;j+=256) s_eix[j]=eix[row0+j];
  }
  __syncthreads();
  int npair=(cnt+1)>>1;
  for (int p=0;p<npair;p++){
    int ne=cnt-2*p; if(ne>2) ne=2;
    int eA=s_eix[2*p], eB=(ne>1)?s_eix[2*p+1]:eA;
    int sA=snd[eA], sB=snd[eB];
    // ---- stage: senders, wigT (transposed, padded [25][20]), rad, attn ----
    {
      const float4* xa=(const float4*)(xn+(size_t)sA*1600);
      const float4* xb=(const float4*)(xn+(size_t)sB*1600);
      for (int j=tid;j<800;j+=256){
        int ed=(j>=400)?1:0, jj=j-400*ed;
        ((float4*)s_snd[ed])[jj] = ed? xb[jj] : xa[jj];
      }
      for (int j=tid;j<1000;j+=256){
        int ed=(j>=500)?1:0, jj=j-500*ed;
        int l=jj/20, m=jj-20*l;
        int e=ed?eB:eA;
        s_rotT[ed][l*20+m]=(m<19)? wig[(size_t)e*475+m*25+l] : 0.0f;
      }
      for (int j=tid;j<192;j+=256){
        int ed=(j>=96)?1:0, jj=j-96*ed;
        int e=ed?eB:eA;
        ((float4*)s_rad[ed])[jj]=((const float4*)(radb+(size_t)e*384))[jj];
      }
      if (tid<16){
        int ed=tid>>3, hd=tid&7;
        int e=ed?eB:eA;
        s_attn[ed][hd]=__expf(logits[(size_t)e*8+hd]-mx[n*8+hd])/(den[n*8+hd]+1e-12f);
      }
    }
    __syncthreads();
    // ---- msg: [19][128] = wigT-rotate(cat) * rad ; 4 m-rows per item ----
    for (int sI=tid;sI<320;sI+=256){
      int ed=(sI>=160)?1:0, s2=sI-160*ed;
      int mq=s2>>5, k4=s2&31;
      if (ed<ne){
        const float4* colbase=(k4<16)?((const float4*)s_snd[ed]+k4):((const float4*)s_recv+(k4-16));
        const float* wT=s_rotT[ed];
        float4 r0=make_float4(0,0,0,0),r1=r0,r2=r0,r3=r0;
        #pragma unroll
        for (int l=0;l<25;l++){
          float4 cv=colbase[l*16];
          float4 wq=((const float4*)(wT+l*20))[mq];
          r0.x+=wq.x*cv.x; r0.y+=wq.x*cv.y; r0.z+=wq.x*cv.z; r0.w+=wq.x*cv.w;
          r1.x+=wq.y*cv.x; r1.y+=wq.y*cv.y; r1.z+=wq.y*cv.z; r1.w+=wq.y*cv.w;
          r2.x+=wq.z*cv.x; r2.y+=wq.z*cv.y; r2.z+=wq.z*cv.z; r2.w+=wq.z*cv.w;
          r3.x+=wq.w*cv.x; r3.y+=wq.w*cv.y; r3.z+=wq.w*cv.z; r3.w+=wq.w*cv.w;
        }
        float4* MV=(float4*)s_mv[ed];
        const float4* RD=(const float4*)s_rad[ed];
        int m0=4*mq;
        {
          float4 rv=RD[d_mg[m0]*32+k4];
          r0.x*=rv.x; r0.y*=rv.y; r0.z*=rv.z; r0.w*=rv.w; MV[m0*32+k4]=r0;
        }
        if (m0+1<19){ float4 rv=RD[d_mg[m0+1]*32+k4]; r1.x*=rv.x; r1.y*=rv.y; r1.z*=rv.z; r1.w*=rv.w; MV[(m0+1)*32+k4]=r1; }
        if (m0+2<19){ float4 rv=RD[d_mg[m0+2]*32+k4]; r2.x*=rv.x; r2.y*=rv.y; r2.z*=rv.z; r2.w*=rv.w; MV[(m0+2)*32+k4]=r2; }
        if (m0+3<19){ float4 rv=RD[d_mg[m0+3]*32+k4]; r3.x*=rv.x; r3.y*=rv.y; r3.z*=rv.z; r3.w*=rv.w; MV[(m0+3)*32+k4]=r3; }
      }
    }
    __syncthreads();
    // ---- vv = (msg @ Wsv) * attn : 128 items (tid<128), others load winvT ----
    float4 racc[12];
    int wg=(tid>>5)&3, ved=(tid>>4)&1, vc8=tid&15;
    bool vact=(tid<128)&&(ved<ne);
    if (tid<128){
      if (vact){
        float va=s_attn[ved][vc8>>1];   // head = (8*c8)/16 = c8>>1
        const float4* W=(const float4*)(wsv+(size_t)d_g4w[wg]*16384);
        const float4* M=(const float4*)s_mv[ved];
        if (wg==0) vv_body<5>(d_g4m[0],M,W,vc8,va,racc);
        else if (wg==1) vv_body<4>(d_g4m[1],M,W,vc8,va,racc);
        else if (wg==2) vv_body<4>(d_g4m[2],M,W,vc8,va,racc);
        else vv_body<6>(d_g4m[3],M,W,vc8,va,racc);
      }
    } else {
      // load winvT [19][28] (l padded 25->28)
      for (int j=tid-128;j<1064;j+=128){
        int ed=(j>=532)?1:0, jj=j-532*ed;
        int m=jj/28, l=jj-28*m;
        int e=ed?eB:eA;
        s_rotT[ed][m*28+l]=(l<25)? winv[(size_t)e*475+l*19+m] : 0.0f;
      }
    }
    __syncthreads();
    if (vact){
      float4* MV=(float4*)s_mv[ved];
      if (wg==0) vv_write<5>(d_g4m[0],MV,vc8,racc);
      else if (wg==1) vv_write<4>(d_g4m[1],MV,vc8,racc);
      else if (wg==2) vv_write<4>(d_g4m[2],MV,vc8,racc);
      else vv_write<6>(d_g4m[3],MV,vc8,racc);
    }
    __syncthreads();
    // ---- oe = vv @ projW : 64 items ----
    if (tid<64){
      int wg2=(tid>>4)&3, ed2=(tid>>3)&1, c8=tid&7;
      if (ed2<ne){
        const float4* P=(const float4*)(projW+(size_t)d_g4w[wg2]*8192);
        const float4* V=(const float4*)s_mv[ed2];
        float4* OE=(float4*)s_oe[ed2];
        if (wg2==0) proj_body<5>(d_g4m[0],V,P,c8,OE);
        else if (wg2==1) proj_body<4>(d_g4m[1],V,P,c8,OE);
        else if (wg2==2) proj_body<4>(d_g4m[2],V,P,c8,OE);
        else proj_body<6>(d_g4m[3],V,P,c8,OE);
      }
    }
    __syncthreads();
    // ---- rotate back via winvT, both edges folded; 4 l-rows per item ----
    if (tid<112){
      int lq=tid>>4, c4=tid&15;
      float4 r0,r1,r2,r3;
      int l0=4*lq;
      float4* A=(float4*)s_acc;
      r0=A[l0*16+c4];
      r1=(l0+1<25)?A[(l0+1)*16+c4]:make_float4(0,0,0,0);
      r2=(l0+2<25)?A[(l0+2)*16+c4]:make_float4(0,0,0,0);
      r3=(l0+3<25)?A[(l0+3)*16+c4]:make_float4(0,0,0,0);
      for (int ed=0;ed<ne;ed++){
        const float* vT=s_rotT[ed];
        const float4* OE=(const float4*)s_oe[ed];
        #pragma unroll
        for (int m=0;m<19;m++){
          float4 ov=OE[m*16+c4];
          float4 wq=((const float4*)(vT+m*28))[lq];
          r0.x+=wq.x*ov.x; r0.y+=wq.x*ov.y; r0.z+=wq.x*ov.z; r0.w+=wq.x*ov.w;
          r1.x+=wq.y*ov.x; r1.y+=wq.y*ov.y; r1.z+=wq.y*ov.z; r1.w+=wq.y*ov.w;
          r2.x+=wq.z*ov.x; r2.y+=wq.z*ov.y; r2.z+=wq.z*ov.z; r2.w+=wq.z*ov.w;
          r3.x+=wq.w*ov.x; r3.y+=wq.w*ov.y; r3.z+=wq.w*ov.z; r3.w+=wq.w*ov.w;
        }
      }
      A[l0*16+c4]=r0;
      if (l0+1<25) A[(l0+1)*16+c4]=r1;
      if (l0+2<25) A[(l0+2)*16+c4]=r2;
      if (l0+3<25) A[(l0+3)*16+c4]=r3;
    }
    __syncthreads();
  }
  float4* xp=(float4*)(x+(size_t)n*1600);
  for (int j=tid;j<400;j+=256){
    float4 cur=xp[j], av=((float4*)s_acc)[j];
    cur.x+=av.x; cur.y+=av.y; cur.z+=av.z; cur.w+=av.w;
    xp[j]=cur;
  }
}

// ---------------- S2 grid FFN ----------------
__global__ __launch_bounds__(256) void grid_ffn_kernel(const float* __restrict__ xn,
    const float* __restrict__ tg, const float* __restrict__ fg,
    const float* __restrict__ W1, const float* __restrict__ b1, const float* __restrict__ W2,
    float* __restrict__ x, int N){
  int n = blockIdx.x, tid = threadIdx.x;
  __shared__ float s_xn[1600];
  __shared__ float s_W2[8192];
  __shared__ float s_b1[128];
  __shared__ float s_g[4][64];
  __shared__ float s_hid[4][128];
  __shared__ float s_o[4][64];
  const float* xr = xn + (size_t)n*1600;
  for (int j=tid;j<1600;j+=256) s_xn[j]=xr[j];
  {
    const float4* src=(const float4*)W2;
    float4* dst=(float4*)s_W2;
    for (int j=tid;j<2048;j+=256) dst[j]=src[j];
  }
  if (tid<128) s_b1[tid]=b1[tid];
  float accv[7];
  #pragma unroll
  for (int t=0;t<7;t++) accv[t]=0.0f;
  __syncthreads();
  for (int gp=0; gp<GPTS; gp+=4){
    int gpl=tid>>6, c=tid&63;
    {
      float a=0;
      #pragma unroll
      for (int l=0;l<25;l++) a += tg[(gp+gpl)*25+l]*s_xn[l*64+c];
      s_g[gpl][c]=a;
    }
    __syncthreads();
    {
      int hh=tid&127, gh=tid>>7;
      #pragma unroll
      for (int q=0;q<2;q++){
        int gg=gh+2*q;
        float h=s_b1[hh];
        #pragma unroll
        for (int cc=0;cc<64;cc++) h += s_g[gg][cc]*W1[cc*128+hh];
        s_hid[gg][hh]=silu_f(h);
      }
    }
    __syncthreads();
    {
      float o=0;
      #pragma unroll
      for (int hh=0;hh<128;hh++) o += s_hid[gpl][hh]*s_W2[hh*64+c];
      s_o[gpl][c]=o;
    }
    __syncthreads();
    {
      int t=0;
      for (int idx=tid; idx<1600; idx+=256, t++){
        int l=idx>>6, cc=idx&63;
        float s=0;
        #pragma unroll
        for (int g2=0; g2<4; g2++) s += fg[l*288+gp+g2]*s_o[g2][cc];
        accv[t]+=s;
      }
    }
    __syncthreads();
  }
  {
    int t=0;
    for (int idx=tid; idx<1600; idx+=256, t++) x[(size_t)n*1600+idx] += accv[t];
  }
}

// ---------------- final energy head ----------------
__global__ __launch_bounds__(256) void energy_kernel(const float* __restrict__ xn,
    const float* __restrict__ tg, const float* __restrict__ fg,
    const float* __restrict__ W1, const float* __restrict__ b1,
    const float* __restrict__ W2, const float* __restrict__ b2,
    float* __restrict__ out, int N){
  int n = blockIdx.x, tid = threadIdx.x;
  __shared__ float s_xn[1600];
  __shared__ float s_W1[8192];
  __shared__ float s_b1[128];
  __shared__ float s_w2[128];
  __shared__ float s_g[4][64];
  __shared__ float s_hid[4][128];
  __shared__ float s_red[4][64];
  const float* xr = xn + (size_t)n*1600;
  for (int j=tid;j<1600;j+=256) s_xn[j]=xr[j];
  {
    const float4* src=(const float4*)W1;
    float4* dst=(float4*)s_W1;
    for (int j=tid;j<2048;j+=256) dst[j]=src[j];
  }
  if (tid<128){ s_b1[tid]=b1[tid]; s_w2[tid]=W2[tid]; }
  float b2v = b2[0];
  float priv = 0.0f;
  __syncthreads();
  for (int gp=0; gp<GPTS; gp+=4){
    int gpl=tid>>6, c=tid&63;
    {
      float a=0;
      #pragma unroll
      for (int l=0;l<25;l++) a += tg[(gp+gpl)*25+l]*s_xn[l*64+c];
      s_g[gpl][c]=a;
    }
    __syncthreads();
    {
      int hh=tid&127, gh=tid>>7;
      #pragma unroll
      for (int q=0;q<2;q++){
        int gg=gh+2*q;
        float h=s_b1[hh];
        #pragma unroll
        for (int cc=0;cc<64;cc++) h += s_g[gg][cc]*s_W1[cc*128+hh];
        s_hid[gg][hh]=silu_f(h);
      }
    }
    __syncthreads();
    {
      float part = s_hid[gpl][c]*s_w2[c] + s_hid[gpl][c+64]*s_w2[c+64];
      s_red[gpl][c]=part;
    }
    __syncthreads();
    if (tid<4){
      float sum=0;
      #pragma unroll
      for (int q=0;q<64;q++) sum += s_red[tid][q];
      priv += fg[gp+tid]*(sum+b2v);
    }
    __syncthreads();
  }
  if (tid<4) s_red[0][tid]=priv;
  __syncthreads();
  if (tid==0) out[n]=(s_red[0][0]+s_red[0][1]+s_red[0][2]+s_red[0][3])*(1.0f/2000.0f);
}

extern "C" void kernel_launch(void* const* d_in, const int* in_sizes, int n_in,
                              void* d_out, int out_size, void* d_ws, size_t ws_size,
                              hipStream_t stream){
  (void)n_in; (void)out_size; (void)ws_size;
  const float* ev   = (const float*)d_in[0];
  const float* wig  = (const float*)d_in[1];
  const float* winv = (const float*)d_in[2];
  const float* spe  = (const float*)d_in[3];
  const float* ese  = (const float*)d_in[4];
  const float* degW1= (const float*)d_in[5];
  const float* degb1= (const float*)d_in[6];
  const float* degW2= (const float*)d_in[7];
  const float* degb2= (const float*)d_in[8];
  const float* n1w  = (const float*)d_in[9];
  const float* radW1= (const float*)d_in[10];
  const float* radb1= (const float*)d_in[11];
  const float* radW2= (const float*)d_in[12];
  const float* radb2= (const float*)d_in[13];
  const float* so2W = (const float*)d_in[14];
  const float* aW   = (const float*)d_in[15];
  const float* aV   = (const float*)d_in[16];
  const float* vW   = (const float*)d_in[17];
  const float* pW   = (const float*)d_in[18];
  const float* n2w  = (const float*)d_in[19];
  const float* fW1  = (const float*)d_in[20];
  const float* fb1  = (const float*)d_in[21];
  const float* fW2  = (const float*)d_in[22];
  const float* tg   = (const float*)d_in[23];
  const float* fg   = (const float*)d_in[24];
  const float* fnw  = (const float*)d_in[25];
  const float* enW1 = (const float*)d_in[26];
  const float* enb1 = (const float*)d_in[27];
  const float* enW2 = (const float*)d_in[28];
  const float* enb2 = (const float*)d_in[29];
  const int* nsp = (const int*)d_in[30];
  const int* snd = (const int*)d_in[31];
  const int* rcv = (const int*)d_in[32];
  int N = in_sizes[30];
  int E = in_sizes[31];
  float* out = (float*)d_out;

  float* ws = (float*)d_ws;
  size_t off = 0;
  float* radbuf = ws + off; off += (size_t)E*384;
  float* logits = ws + off; off += (size_t)E*8;
  float* mx     = ws + off; off += (size_t)N*8;
  float* den    = ws + off; off += (size_t)N*8;
  float* x      = ws + off; off += (size_t)N*1600;
  float* xn     = ws + off; off += (size_t)N*1600;
  float* wsvbuf = ws + off; off += (size_t)6*16384;
  int* cnt      = (int*)(ws + off); off += (size_t)N;
  int* rowptr   = (int*)(ws + off); off += (size_t)(N+1);
  int* fill     = (int*)(ws + off); off += (size_t)N;
  int* eixbuf   = (int*)(ws + off); off += (size_t)E;

  // CSR by receiver + fused weights
  zero_cnt_kernel<<<(N+255)/256, 256, 0, stream>>>(cnt, N);
  csr_count_kernel<<<(E+255)/256, 256, 0, stream>>>(rcv, cnt, E);
  csr_scan_kernel<<<1, 256, 0, stream>>>(cnt, rowptr, fill, N);
  csr_fill_kernel<<<(E+255)/256, 256, 0, stream>>>(rcv, fill, eixbuf, E);
  wsv_kernel<<<6, 256, 0, stream>>>(so2W, vW, wsvbuf);

  deg_gather_kernel<<<N, 256, 0, stream>>>(ev, ese, nsp, spe, degW1, degb1, degW2, degb2,
                                           winv, snd, rowptr, eixbuf, x, N);

  for (int i=0;i<2;i++){
    rmsnorm_kernel<<<N, 256, 0, stream>>>(x, n1w + (size_t)i*320, xn, N);
    init_mxden_kernel<<<(N*8+255)/256, 256, 0, stream>>>(mx, den, N);
    rad_kernel<<<(E+3)/4, 256, 0, stream>>>(ev, ese, nsp, radW1 + (size_t)i*DIN*128, radb1 + (size_t)i*128,
                                            radW2 + (size_t)i*128*384, radb2 + (size_t)i*384,
                                            snd, rcv, radbuf, E);
    logits_kernel<<<E, 256, 0, stream>>>(xn, wig, radbuf, so2W + (size_t)i*24576,
                                         aW + (size_t)i*64*256, aV + (size_t)i*256,
                                         snd, rcv, logits, mx, E);
    den_kernel<<<(E*8+255)/256, 256, 0, stream>>>(logits, mx, rcv, den, E);
    attn_gather_kernel<<<N, 256, 0, stream>>>(xn, wig, winv, radbuf,
                                              wsvbuf + (size_t)i*49152, pW + (size_t)i*24576,
                                              logits, mx, den, snd, rowptr, eixbuf, x, N);
    rmsnorm_kernel<<<N, 256, 0, stream>>>(x, n2w + (size_t)i*320, xn, N);
    grid_ffn_kernel<<<N, 256, 0, stream>>>(xn, tg, fg, fW1 + (size_t)i*8192, fb1 + (size_t)i*128,
                                           fW2 + (size_t)i*8192, x, N);
  }
  rmsnorm_kernel<<<N, 256, 0, stream>>>(x, fnw, xn, N);
  energy_kernel<<<N, 256, 0, stream>>>(xn, tg, fg, enW1, enb1, enW2, enb2, out, N);
}

// Round 6
// 8399.217 us; speedup vs baseline: 2.7446x; 2.7446x over previous
//
#include <hip/hip_runtime.h>
#include <hip/hip_bf16.h>
#include <math.h>

// EquiformerV2 block, fp32 activations. Round 6: round-4 attn structure with
// fused so2@val weights in bf16, 4-row register-blocked phases, 192+ active threads.
// E=40000 edges, N=2000 nodes, C=64, L2=25, M2=19, NL=2.

#define NRBF 600
#define DIN 728
#define GPTS 288
#define MAXE 160

__constant__ int d_mg[19] = {0,1,0,1,2,1,0,1,2,2,1,0,1,2,2,1,0,1,2};
__constant__ int d_loc[25] = {0,1,1,1,2,2,2,2,2,3,3,3,3,3,3,3,4,4,4,4,4,4,4,4,4};
// 6 row-quads (pad by duplicating a row of the same m-group; dup writes are benign)
__constant__ int d_rq[6][4] = {{0,2,6,11},{16,16,16,16},{1,3,5,7},{10,12,15,17},{4,8,9,13},{14,18,18,18}};
__constant__ int d_rqg[6] = {0,0,1,1,2,2};

__device__ inline float silu_f(float v){ return v/(1.0f+__expf(-v)); }
__device__ inline float bf2f(unsigned short u){ return __uint_as_float(((unsigned)u)<<16); }
__device__ inline unsigned short f2bf(float f){
  unsigned b=__float_as_uint(f);
  return (unsigned short)((b + 0x7FFF + ((b>>16)&1)) >> 16);
}

__device__ inline void atomicMaxF(float* addr, float val){
  int* ia=(int*)addr;
  int old=*ia;
  while (__int_as_float(old) < val){
    int assumed=old;
    old = atomicCAS(ia, assumed, __float_as_int(val));
    if (old == assumed) break;
  }
}

// ---------------- CSR build ----------------
__global__ __launch_bounds__(256) void zero_cnt_kernel(int* cnt, int N){
  int i = blockIdx.x*256+threadIdx.x;
  if (i<N) cnt[i]=0;
}
__global__ __launch_bounds__(256) void csr_count_kernel(const int* __restrict__ rcv, int* cnt, int E){
  int i = blockIdx.x*256+threadIdx.x;
  if (i<E) atomicAdd(&cnt[rcv[i]],1);
}
__global__ __launch_bounds__(256) void csr_scan_kernel(const int* __restrict__ cnt,
    int* rowptr, int* fill, int N){
  __shared__ int s_part[256];
  int tid=threadIdx.x;
  int chunk=(N+255)/256;
  int lvals[12];
  int base=tid*chunk;
  int lsum=0;
  for (int i=0;i<chunk && i<12;i++){
    int v=(base+i<N)?cnt[base+i]:0;
    lvals[i]=lsum; lsum+=v;
  }
  s_part[tid]=lsum;
  __syncthreads();
  if (tid==0){
    int run=0;
    for (int t=0;t<256;t++){ int v=s_part[t]; s_part[t]=run; run+=v; }
  }
  __syncthreads();
  int off=s_part[tid];
  for (int i=0;i<chunk && i<12;i++){
    if (base+i<N){ rowptr[base+i]=off+lvals[i]; fill[base+i]=off+lvals[i]; }
  }
  if (tid==255) rowptr[N]=off+lsum;
}
__global__ __launch_bounds__(256) void csr_fill_kernel(const int* __restrict__ rcv,
    int* fill, int* eix, int E){
  int i = blockIdx.x*256+threadIdx.x;
  if (i<E){ int p=atomicAdd(&fill[rcv[i]],1); eix[p]=i; }
}

// ---------------- fused so2W@valW -> bf16 wsvb [6][128][128] ----------------
__global__ __launch_bounds__(256) void wsvb_kernel(const float* __restrict__ so2W,
    const float* __restrict__ valW, unsigned short* __restrict__ wsvb){
  int i=blockIdx.x/3, g=blockIdx.x%3;
  const float* A = so2W + (size_t)i*24576 + g*8192;   // [128][64]
  const float* B = valW + (size_t)i*24576 + g*8192;   // [64][128]
  unsigned short* C = wsvb + (size_t)blockIdx.x*16384;
  __shared__ float sB[8192];
  for (int j=threadIdx.x;j<2048;j+=256) ((float4*)sB)[j]=((const float4*)B)[j];
  __syncthreads();
  for (int idx=threadIdx.x; idx<16384; idx+=256){
    int k=idx>>7, j=idx&127;
    float acc=0;
    #pragma unroll 4
    for (int o=0;o<64;o++) acc += A[k*64+o]*sB[o*128+j];
    C[idx]=f2bf(acc);
  }
}

// ---------------- projW -> bf16 [6][128][64] ----------------
__global__ __launch_bounds__(256) void projb_kernel(const float* __restrict__ pW,
    unsigned short* __restrict__ projb){
  const float* src = pW + (size_t)blockIdx.x*8192;
  unsigned short* dst = projb + (size_t)blockIdx.x*8192;
  for (int idx=threadIdx.x; idx<8192; idx+=256) dst[idx]=f2bf(src[idx]);
}

// ---------------- edge degree embedding, gather form (per node) ----------------
__global__ __launch_bounds__(256) void deg_gather_kernel(const float* __restrict__ ev,
    const float* __restrict__ ese, const int* __restrict__ nsp, const float* __restrict__ spe,
    const float* __restrict__ W1, const float* __restrict__ b1,
    const float* __restrict__ W2, const float* __restrict__ b2,
    const float* __restrict__ winv, const int* __restrict__ snd,
    const int* __restrict__ rowptr, const int* __restrict__ eix,
    float* __restrict__ x, int N){
  int n = blockIdx.x, tid = threadIdx.x;
  __shared__ float s_ee[4][DIN];
  __shared__ float s_h1[4][128];
  __shared__ float s_h2[4][1216];
  __shared__ float s_part[256][4];
  __shared__ float s_acc[1600];
  __shared__ float s_winv[475];
  __shared__ int s_eix[MAXE];
  __shared__ float s_d[4]; __shared__ int s_ss[4]; __shared__ int s_rs[4];
  int row0=rowptr[n];
  int cnt=rowptr[n+1]-row0; if (cnt>MAXE) cnt=MAXE;
  {
    float4 z={0,0,0,0};
    for (int j=tid;j<400;j+=256) ((float4*)s_acc)[j]=z;
    for (int j=tid;j<cnt;j+=256) s_eix[j]=eix[row0+j];
  }
  __syncthreads();
  int nq=(cnt+3)>>2;
  for (int q=0;q<nq;q++){
    int qb=q*4;
    int ne=cnt-qb; if (ne>4) ne=4;
    if (tid<4){
      int le=qb+tid;
      if (le<cnt){
        int e=s_eix[le];
        float vx=ev[3*e], vy=ev[3*e+1], vz=ev[3*e+2];
        s_d[tid]=sqrtf(vx*vx+vy*vy+vz*vz+1e-12f);
        s_ss[tid]=nsp[snd[e]];
        s_rs[tid]=nsp[n];
      } else { s_d[tid]=0.0f; s_ss[tid]=0; s_rs[tid]=0; }
    }
    __syncthreads();
    const float step = 5.0f/599.0f;
    const float inv_std = 1.0f/(2.0f*step);
    for (int j=tid;j<4*DIN;j+=256){
      int le=j/DIN, jj=j%DIN;
      float v;
      if (jj<NRBF){ float t=(s_d[le]-jj*step)*inv_std; v=__expf(-0.5f*t*t); }
      else if (jj<NRBF+64) v=ese[s_ss[le]*128+(jj-NRBF)];
      else v=ese[s_rs[le]*128+64+(jj-NRBF-64)];
      s_ee[le][jj]=v;
    }
    __syncthreads();
    {
      int o=tid&127, half=tid>>7, i0=half*364;
      float a0=0,a1=0,a2=0,a3=0;
      for (int i=i0;i<i0+364;i++){
        float w=W1[i*128+o];
        a0+=s_ee[0][i]*w; a1+=s_ee[1][i]*w; a2+=s_ee[2][i]*w; a3+=s_ee[3][i]*w;
      }
      s_part[tid][0]=a0; s_part[tid][1]=a1; s_part[tid][2]=a2; s_part[tid][3]=a3;
    }
    __syncthreads();
    if (tid<128){
      float bb=b1[tid];
      #pragma unroll
      for (int le=0;le<4;le++){
        float a=s_part[tid][le]+s_part[tid+128][le]+bb;
        s_h1[le][tid]=silu_f(a);
      }
    }
    __syncthreads();
    for (int m=tid;m<1216;m+=256){
      float bb=b2[m];
      float a0=bb,a1=bb,a2=bb,a3=bb;
      for (int o=0;o<128;o++){
        float w=W2[o*1216+m];
        a0+=s_h1[0][o]*w; a1+=s_h1[1][o]*w; a2+=s_h1[2][o]*w; a3+=s_h1[3][o]*w;
      }
      s_h2[0][m]=a0; s_h2[1][m]=a1; s_h2[2][m]=a2; s_h2[3][m]=a3;
    }
    __syncthreads();
    for (int le2=0;le2<ne;le2++){
      int e=s_eix[qb+le2];
      for (int j=tid;j<475;j+=256) s_winv[j]=winv[(size_t)e*475+j];
      __syncthreads();
      const float4* H2=(const float4*)s_h2[le2];
      for (int sI=tid;sI<400;sI+=256){
        int l=sI>>4, c4=sI&15;
        const float* wr=s_winv+l*19;
        float4 acc={0,0,0,0};
        #pragma unroll
        for (int m=0;m<19;m++){
          float w=wr[m];
          float4 hv=H2[m*16+c4];
          acc.x+=w*hv.x; acc.y+=w*hv.y; acc.z+=w*hv.z; acc.w+=w*hv.w;
        }
        float4* A=(float4*)s_acc;
        float4 cur=A[sI];
        cur.x+=acc.x; cur.y+=acc.y; cur.z+=acc.z; cur.w+=acc.w;
        A[sI]=cur;
      }
      __syncthreads();
    }
  }
  int sp=nsp[n];
  for (int j=tid;j<1600;j+=256){
    int l=j>>6, c=j&63;
    float base=(l==0)?spe[sp*64+c]:0.0f;
    x[(size_t)n*1600+j]=base+0.05f*s_acc[j];
  }
}

// ---------------- per-degree RMS norm ----------------
__global__ __launch_bounds__(256) void rmsnorm_kernel(const float* __restrict__ x,
    const float* __restrict__ w, float* __restrict__ xn, int N){
  int n = blockIdx.x, tid = threadIdx.x;
  __shared__ float s_x[1600];
  __shared__ float s_part[256];
  __shared__ float s_ms[64];
  const float* xr = x + (size_t)n*1600;
  for (int j=tid;j<1600;j+=256) s_x[j]=xr[j];
  __syncthreads();
  {
    int c = tid&63, seg = tid>>6;
    float acc=0;
    for (int l=seg;l<25;l+=4){ float v=s_x[l*64+c]; acc+=v*v; }
    s_part[tid]=acc;
  }
  __syncthreads();
  if (tid<64){
    float m=(s_part[tid]+s_part[tid+64]+s_part[tid+128]+s_part[tid+192])*(1.0f/25.0f);
    s_ms[tid]=rsqrtf(m+1e-6f);
  }
  __syncthreads();
  float* xo = xn + (size_t)n*1600;
  for (int j=tid;j<1600;j+=256){
    int l=j>>6, c=j&63;
    xo[j]=s_x[j]*s_ms[c]*w[d_loc[l]*64+c];
  }
}

__global__ __launch_bounds__(256) void init_mxden_kernel(float* mx, float* den, int N){
  int idx = blockIdx.x*256+threadIdx.x;
  if (idx < N*8){ mx[idx]=-3.0e38f; den[idx]=0.0f; }
}

// ---------------- radial MLP (edge-parallel, 4 edges/block) ----------------
__global__ __launch_bounds__(256) void rad_kernel(const float* __restrict__ ev,
    const float* __restrict__ ese, const int* __restrict__ nsp,
    const float* __restrict__ W1, const float* __restrict__ b1,
    const float* __restrict__ W2, const float* __restrict__ b2,
    const int* __restrict__ snd, const int* __restrict__ rcv,
    float* __restrict__ radb, int E){
  int e0 = blockIdx.x*4, tid = threadIdx.x;
  __shared__ float s_ee[4][DIN];
  __shared__ float s_h1[4][128];
  __shared__ float s_part[256][4];
  __shared__ float s_d[4]; __shared__ int s_ss[4]; __shared__ int s_rs[4];
  int ne = E - e0; if (ne > 4) ne = 4;
  if (tid<4){
    int e=e0+tid;
    if (e<E){
      float vx=ev[3*e], vy=ev[3*e+1], vz=ev[3*e+2];
      s_d[tid]=sqrtf(vx*vx+vy*vy+vz*vz+1e-12f);
      s_ss[tid]=nsp[snd[e]]; s_rs[tid]=nsp[rcv[e]];
    } else { s_d[tid]=0.0f; s_ss[tid]=0; s_rs[tid]=0; }
  }
  __syncthreads();
  const float step = 5.0f/599.0f;
  const float inv_std = 1.0f/(2.0f*step);
  for (int j=tid;j<4*DIN;j+=256){
    int le=j/DIN, jj=j%DIN;
    float v;
    if (jj<NRBF){ float t=(s_d[le]-jj*step)*inv_std; v=__expf(-0.5f*t*t); }
    else if (jj<NRBF+64) v=ese[s_ss[le]*128+(jj-NRBF)];
    else v=ese[s_rs[le]*128+64+(jj-NRBF-64)];
    s_ee[le][jj]=v;
  }
  __syncthreads();
  {
    int o=tid&127, half=tid>>7, i0=half*364;
    float a0=0,a1=0,a2=0,a3=0;
    for (int i=i0;i<i0+364;i++){
      float w=W1[i*128+o];
      a0+=s_ee[0][i]*w; a1+=s_ee[1][i]*w; a2+=s_ee[2][i]*w; a3+=s_ee[3][i]*w;
    }
    s_part[tid][0]=a0; s_part[tid][1]=a1; s_part[tid][2]=a2; s_part[tid][3]=a3;
  }
  __syncthreads();
  if (tid<128){
    float bb=b1[tid];
    #pragma unroll
    for (int le=0;le<4;le++){
      float a=s_part[tid][le]+s_part[tid+128][le]+bb;
      s_h1[le][tid]=silu_f(a);
    }
  }
  __syncthreads();
  for (int m=tid;m<384;m+=256){
    float bb=b2[m];
    float a0=bb,a1=bb,a2=bb,a3=bb;
    for (int o=0;o<128;o++){
      float w=W2[o*384+m];
      a0+=s_h1[0][o]*w; a1+=s_h1[1][o]*w; a2+=s_h1[2][o]*w; a3+=s_h1[3][o]*w;
    }
    if (0<ne) radb[(size_t)(e0+0)*384+m]=a0;
    if (1<ne) radb[(size_t)(e0+1)*384+m]=a1;
    if (2<ne) radb[(size_t)(e0+2)*384+m]=a2;
    if (3<ne) radb[(size_t)(e0+3)*384+m]=a3;
  }
}

// ---------------- pass 1: m=0 path -> alpha logits ----------------
__global__ __launch_bounds__(256) void logits_kernel(const float* __restrict__ xn,
    const float* __restrict__ wig, const float* __restrict__ radb,
    const float* __restrict__ so2W, const float* __restrict__ alphaW, const float* __restrict__ alphaV,
    const int* __restrict__ snd, const int* __restrict__ rcv,
    float* __restrict__ logits, float* __restrict__ mx, int E){
  int e = blockIdx.x, tid = threadIdx.x;
  __shared__ float s_cat[3200];
  __shared__ float s_wig0[25];
  __shared__ float s_msg0[128];
  __shared__ float s_sh0[64];
  __shared__ float s_a[256];
  int s = snd[e], r = rcv[e];
  const float4* xs4 = (const float4*)(xn + (size_t)s*1600);
  const float4* xr4 = (const float4*)(xn + (size_t)r*1600);
  float4* cat4 = (float4*)s_cat;
  for (int j=tid;j<400;j+=256){
    int l=j>>4, c4=j&15;
    cat4[l*32+c4]    = xs4[j];
    cat4[l*32+16+c4] = xr4[j];
  }
  if (tid<25) s_wig0[tid]=wig[(size_t)e*475+tid];
  __syncthreads();
  if (tid<128){
    float acc=0;
    #pragma unroll
    for (int l=0;l<25;l++) acc += s_wig0[l]*s_cat[l*128+tid];
    s_msg0[tid]=acc*radb[(size_t)e*384+tid];
  }
  __syncthreads();
  if (tid<64){
    float acc=0;
    #pragma unroll
    for (int k=0;k<128;k++) acc += s_msg0[k]*so2W[k*64+tid];
    s_sh0[tid]=silu_f(acc);
  }
  __syncthreads();
  {
    float acc=0;
    #pragma unroll
    for (int o=0;o<64;o++) acc += s_sh0[o]*alphaW[o*256+tid];
    s_a[tid]=silu_f(acc)*alphaV[tid];
  }
  __syncthreads();
  if (tid<8){
    float lg=0;
    #pragma unroll
    for (int q=0;q<32;q++) lg += s_a[tid*32+q];
    logits[(size_t)e*8+tid]=lg;
    atomicMaxF(&mx[r*8+tid], lg);
  }
}

__global__ __launch_bounds__(256) void den_kernel(const float* __restrict__ logits,
    const float* __restrict__ mx, const int* __restrict__ rcv,
    float* __restrict__ den, int E){
  int idx = blockIdx.x*256+threadIdx.x;
  if (idx >= E*8) return;
  int e = idx>>3, hd = idx&7, r = rcv[e];
  atomicAdd(&den[r*8+hd], __expf(logits[idx]-mx[r*8+hd]));
}

// ---------------- pass 2, gather: per node, loop in-edges ----------------
__global__ __launch_bounds__(256) void attn_gather_kernel(const float* __restrict__ xn,
    const float* __restrict__ wig, const float* __restrict__ winv, const float* __restrict__ radb,
    const unsigned short* __restrict__ wsvb, const unsigned short* __restrict__ projb,
    const float* __restrict__ logits, const float* __restrict__ mx, const float* __restrict__ den,
    const int* __restrict__ snd, const int* __restrict__ rowptr, const int* __restrict__ eix,
    float* __restrict__ x, int N){
  int n = blockIdx.x, tid = threadIdx.x;
  __shared__ float s_cat[3200];   // [25][128] : cols 0..63 sender, 64..127 receiver
  __shared__ float s_mv[2432];    // [19][128] msg -> vv (in place)
  __shared__ float s_oe[1216];    // [19][64]
  __shared__ float s_acc[1600];
  __shared__ float s_wig[475];
  __shared__ float s_winv[475];
  __shared__ float s_rad[384];
  __shared__ float s_attn[8];
  __shared__ int s_eix[MAXE];
  int row0=rowptr[n];
  int cnt=rowptr[n+1]-row0; if (cnt>MAXE) cnt=MAXE;
  {
    const float4* xr4=(const float4*)(xn+(size_t)n*1600);
    float4* cat4=(float4*)s_cat;
    for (int j=tid;j<400;j+=256){ int l=j>>4,c4=j&15; cat4[l*32+16+c4]=xr4[j]; }
    float4 z={0,0,0,0};
    for (int j=tid;j<400;j+=256) ((float4*)s_acc)[j]=z;
    for (int j=tid;j<cnt;j+=256) s_eix[j]=eix[row0+j];
  }
  __syncthreads();
  for (int le=0;le<cnt;le++){
    int e=s_eix[le];
    int s=snd[e];
    // ---- stage ----
    {
      const float4* xs4=(const float4*)(xn+(size_t)s*1600);
      float4* cat4=(float4*)s_cat;
      for (int j=tid;j<400;j+=256){ int l=j>>4,c4=j&15; cat4[l*32+c4]=xs4[l*16+c4]; }
    }
    for (int j=tid;j<475;j+=256){ s_wig[j]=wig[(size_t)e*475+j]; s_winv[j]=winv[(size_t)e*475+j]; }
    for (int j=tid;j<96;j+=256) ((float4*)s_rad)[j]=((const float4*)(radb+(size_t)e*384))[j];
    if (tid<8) s_attn[tid]=__expf(logits[(size_t)e*8+tid]-mx[n*8+tid])/(den[n*8+tid]+1e-12f);
    __syncthreads();
    // ---- msg = wig-rotate(cat) * rad : [19][128] ----
    for (int sI=tid;sI<608;sI+=256){
      int m=sI>>5, k4=sI&31;
      const float* wr=s_wig+m*25;
      const float4* catp=(const float4*)s_cat;
      float4 acc={0,0,0,0};
      #pragma unroll
      for (int l=0;l<25;l++){
        float w=wr[l];
        float4 cv=catp[l*32+k4];
        acc.x+=w*cv.x; acc.y+=w*cv.y; acc.z+=w*cv.z; acc.w+=w*cv.w;
      }
      float4 rv=((const float4*)s_rad)[d_mg[m]*32+k4];
      acc.x*=rv.x; acc.y*=rv.y; acc.z*=rv.z; acc.w*=rv.w;
      ((float4*)s_mv)[m*32+k4]=acc;
    }
    __syncthreads();
    // ---- vv = (msg @ wsv_g) * attn : 192 items, 4 rows x 4 cols each (in-place) ----
    float4 va0,va1,va2,va3;
    int rq=tid>>5, c4=tid&31;
    int r0=0,r1=0,r2=0,r3=0;
    bool vact=(tid<192);
    if (vact){
      r0=d_rq[rq][0]; r1=d_rq[rq][1]; r2=d_rq[rq][2]; r3=d_rq[rq][3];
      const ushort4* W=(const ushort4*)(wsvb + (size_t)d_rqg[rq]*16384);
      const float4* M=(const float4*)s_mv;
      va0=make_float4(0,0,0,0); va1=va0; va2=va0; va3=va0;
      #pragma unroll 2
      for (int k4=0;k4<32;k4++){
        float4 a0=M[r0*32+k4], a1=M[r1*32+k4], a2=M[r2*32+k4], a3=M[r3*32+k4];
        ushort4 u0=W[(k4*4+0)*32+c4], u1=W[(k4*4+1)*32+c4], u2=W[(k4*4+2)*32+c4], u3=W[(k4*4+3)*32+c4];
        float4 w0={bf2f(u0.x),bf2f(u0.y),bf2f(u0.z),bf2f(u0.w)};
        float4 w1={bf2f(u1.x),bf2f(u1.y),bf2f(u1.z),bf2f(u1.w)};
        float4 w2={bf2f(u2.x),bf2f(u2.y),bf2f(u2.z),bf2f(u2.w)};
        float4 w3={bf2f(u3.x),bf2f(u3.y),bf2f(u3.z),bf2f(u3.w)};
        va0.x+=a0.x*w0.x+a0.y*w1.x+a0.z*w2.x+a0.w*w3.x;
        va0.y+=a0.x*w0.y+a0.y*w1.y+a0.z*w2.y+a0.w*w3.y;
        va0.z+=a0.x*w0.z+a0.y*w1.z+a0.z*w2.z+a0.w*w3.z;
        va0.w+=a0.x*w0.w+a0.y*w1.w+a0.z*w2.w+a0.w*w3.w;
        va1.x+=a1.x*w0.x+a1.y*w1.x+a1.z*w2.x+a1.w*w3.x;
        va1.y+=a1.x*w0.y+a1.y*w1.y+a1.z*w2.y+a1.w*w3.y;
        va1.z+=a1.x*w0.z+a1.y*w1.z+a1.z*w2.z+a1.w*w3.z;
        va1.w+=a1.x*w0.w+a1.y*w1.w+a1.z*w2.w+a1.w*w3.w;
        va2.x+=a2.x*w0.x+a2.y*w1.x+a2.z*w2.x+a2.w*w3.x;
        va2.y+=a2.x*w0.y+a2.y*w1.y+a2.z*w2.y+a2.w*w3.y;
        va2.z+=a2.x*w0.z+a2.y*w1.z+a2.z*w2.z+a2.w*w3.z;
        va2.w+=a2.x*w0.w+a2.y*w1.w+a2.z*w2.w+a2.w*w3.w;
        va3.x+=a3.x*w0.x+a3.y*w1.x+a3.z*w2.x+a3.w*w3.x;
        va3.y+=a3.x*w0.y+a3.y*w1.y+a3.z*w2.y+a3.w*w3.y;
        va3.z+=a3.x*w0.z+a3.y*w1.z+a3.z*w2.z+a3.w*w3.z;
        va3.w+=a3.x*w0.w+a3.y*w1.w+a3.z*w2.w+a3.w*w3.w;
      }
      float at=s_attn[c4>>2];
      va0.x*=at; va0.y*=at; va0.z*=at; va0.w*=at;
      va1.x*=at; va1.y*=at; va1.z*=at; va1.w*=at;
      va2.x*=at; va2.y*=at; va2.z*=at; va2.w*=at;
      va3.x*=at; va3.y*=at; va3.z*=at; va3.w*=at;
    }
    __syncthreads();
    if (vact){
      float4* MV=(float4*)s_mv;
      MV[r0*32+c4]=va0; MV[r1*32+c4]=va1; MV[r2*32+c4]=va2; MV[r3*32+c4]=va3;
    }
    __syncthreads();
    // ---- oe = vv @ projW_g : 192 items, 4 rows x 2 cols each ----
    if (tid<192){
      int rq2=tid>>5, c2=tid&31;
      int q0=d_rq[rq2][0], q1=d_rq[rq2][1], q2=d_rq[rq2][2], q3=d_rq[rq2][3];
      const ushort2* P=(const ushort2*)(projb + (size_t)d_rqg[rq2]*8192);
      const float4* V=(const float4*)s_mv;
      float2 p0={0,0},p1={0,0},p2={0,0},p3={0,0};
      #pragma unroll 2
      for (int k4=0;k4<32;k4++){
        float4 a0=V[q0*32+k4], a1=V[q1*32+k4], a2=V[q2*32+k4], a3=V[q3*32+k4];
        ushort2 u0=P[(k4*4+0)*32+c2], u1=P[(k4*4+1)*32+c2], u2=P[(k4*4+2)*32+c2], u3=P[(k4*4+3)*32+c2];
        float2 w0={bf2f(u0.x),bf2f(u0.y)};
        float2 w1={bf2f(u1.x),bf2f(u1.y)};
        float2 w2={bf2f(u2.x),bf2f(u2.y)};
        float2 w3={bf2f(u3.x),bf2f(u3.y)};
        p0.x+=a0.x*w0.x+a0.y*w1.x+a0.z*w2.x+a0.w*w3.x;
        p0.y+=a0.x*w0.y+a0.y*w1.y+a0.z*w2.y+a0.w*w3.y;
        p1.x+=a1.x*w0.x+a1.y*w1.x+a1.z*w2.x+a1.w*w3.x;
        p1.y+=a1.x*w0.y+a1.y*w1.y+a1.z*w2.y+a1.w*w3.y;
        p2.x+=a2.x*w0.x+a2.y*w1.x+a2.z*w2.x+a2.w*w3.x;
        p2.y+=a2.x*w0.y+a2.y*w1.y+a2.z*w2.y+a2.w*w3.y;
        p3.x+=a3.x*w0.x+a3.y*w1.x+a3.z*w2.x+a3.w*w3.x;
        p3.y+=a3.x*w0.y+a3.y*w1.y+a3.z*w2.y+a3.w*w3.y;
      }
      float2* OE2=(float2*)s_oe;
      OE2[q0*32+c2]=p0; OE2[q1*32+c2]=p1; OE2[q2*32+c2]=p2; OE2[q3*32+c2]=p3;
    }
    __syncthreads();
    // ---- rotate back (winv) + accumulate in LDS ----
    for (int sI=tid;sI<400;sI+=256){
      int l=sI>>4, c4b=sI&15;
      const float* wr=s_winv+l*19;
      const float4* OE=(const float4*)s_oe;
      float4 acc={0,0,0,0};
      #pragma unroll
      for (int m=0;m<19;m++){
        float w=wr[m];
        float4 ov=OE[m*16+c4b];
        acc.x+=w*ov.x; acc.y+=w*ov.y; acc.z+=w*ov.z; acc.w+=w*ov.w;
      }
      float4* A=(float4*)s_acc;
      float4 cur=A[sI];
      cur.x+=acc.x; cur.y+=acc.y; cur.z+=acc.z; cur.w+=acc.w;
      A[sI]=cur;
    }
    __syncthreads();
  }
  float4* xp=(float4*)(x+(size_t)n*1600);
  for (int j=tid;j<400;j+=256){
    float4 cur=xp[j], av=((float4*)s_acc)[j];
    cur.x+=av.x; cur.y+=av.y; cur.z+=av.z; cur.w+=av.w;
    xp[j]=cur;
  }
}

// ---------------- S2 grid FFN (W1 now staged in LDS) ----------------
__global__ __launch_bounds__(256) void grid_ffn_kernel(const float* __restrict__ xn,
    const float* __restrict__ tg, const float* __restrict__ fg,
    const float* __restrict__ W1, const float* __restrict__ b1, const float* __restrict__ W2,
    float* __restrict__ x, int N){
  int n = blockIdx.x, tid = threadIdx.x;
  __shared__ float s_xn[1600];
  __shared__ float s_W1[8192];
  __shared__ float s_W2[8192];
  __shared__ float s_b1[128];
  __shared__ float s_g[4][64];
  __shared__ float s_hid[4][128];
  __shared__ float s_o[4][64];
  const float* xr = xn + (size_t)n*1600;
  for (int j=tid;j<1600;j+=256) s_xn[j]=xr[j];
  {
    const float4* src1=(const float4*)W1;
    const float4* src2=(const float4*)W2;
    float4* dst1=(float4*)s_W1;
    float4* dst2=(float4*)s_W2;
    for (int j=tid;j<2048;j+=256){ dst1[j]=src1[j]; dst2[j]=src2[j]; }
  }
  if (tid<128) s_b1[tid]=b1[tid];
  float accv[7];
  #pragma unroll
  for (int t=0;t<7;t++) accv[t]=0.0f;
  __syncthreads();
  for (int gp=0; gp<GPTS; gp+=4){
    int gpl=tid>>6, c=tid&63;
    {
      float a=0;
      #pragma unroll
      for (int l=0;l<25;l++) a += tg[(gp+gpl)*25+l]*s_xn[l*64+c];
      s_g[gpl][c]=a;
    }
    __syncthreads();
    {
      int hh=tid&127, gh=tid>>7;
      #pragma unroll
      for (int q=0;q<2;q++){
        int gg=gh+2*q;
        float h=s_b1[hh];
        #pragma unroll
        for (int cc=0;cc<64;cc++) h += s_g[gg][cc]*s_W1[cc*128+hh];
        s_hid[gg][hh]=silu_f(h);
      }
    }
    __syncthreads();
    {
      float o=0;
      #pragma unroll
      for (int hh=0;hh<128;hh++) o += s_hid[gpl][hh]*s_W2[hh*64+c];
      s_o[gpl][c]=o;
    }
    __syncthreads();
    {
      int t=0;
      for (int idx=tid; idx<1600; idx+=256, t++){
        int l=idx>>6, cc=idx&63;
        float s=0;
        #pragma unroll
        for (int g2=0; g2<4; g2++) s += fg[l*288+gp+g2]*s_o[g2][cc];
        accv[t]+=s;
      }
    }
    __syncthreads();
  }
  {
    int t=0;
    for (int idx=tid; idx<1600; idx+=256, t++) x[(size_t)n*1600+idx] += accv[t];
  }
}

// ---------------- final energy head ----------------
__global__ __launch_bounds__(256) void energy_kernel(const float* __restrict__ xn,
    const float* __restrict__ tg, const float* __restrict__ fg,
    const float* __restrict__ W1, const float* __restrict__ b1,
    const float* __restrict__ W2, const float* __restrict__ b2,
    float* __restrict__ out, int N){
  int n = blockIdx.x, tid = threadIdx.x;
  __shared__ float s_xn[1600];
  __shared__ float s_W1[8192];
  __shared__ float s_b1[128];
  __shared__ float s_w2[128];
  __shared__ float s_g[4][64];
  __shared__ float s_hid[4][128];
  __shared__ float s_red[4][64];
  const float* xr = xn + (size_t)n*1600;
  for (int j=tid;j<1600;j+=256) s_xn[j]=xr[j];
  {
    const float4* src=(const float4*)W1;
    float4* dst=(float4*)s_W1;
    for (int j=tid;j<2048;j+=256) dst[j]=src[j];
  }
  if (tid<128){ s_b1[tid]=b1[tid]; s_w2[tid]=W2[tid]; }
  float b2v = b2[0];
  float priv = 0.0f;
  __syncthreads();
  for (int gp=0; gp<GPTS; gp+=4){
    int gpl=tid>>6, c=tid&63;
    {
      float a=0;
      #pragma unroll
      for (int l=0;l<25;l++) a += tg[(gp+gpl)*25+l]*s_xn[l*64+c];
      s_g[gpl][c]=a;
    }
    __syncthreads();
    {
      int hh=tid&127, gh=tid>>7;
      #pragma unroll
      for (int q=0;q<2;q++){
        int gg=gh+2*q;
        float h=s_b1[hh];
        #pragma unroll
        for (int cc=0;cc<64;cc++) h += s_g[gg][cc]*s_W1[cc*128+hh];
        s_hid[gg][hh]=silu_f(h);
      }
    }
    __syncthreads();
    {
      float part = s_hid[gpl][c]*s_w2[c] + s_hid[gpl][c+64]*s_w2[c+64];
      s_red[gpl][c]=part;
    }
    __syncthreads();
    if (tid<4){
      float sum=0;
      #pragma unroll
      for (int q=0;q<64;q++) sum += s_red[tid][q];
      priv += fg[gp+tid]*(sum+b2v);
    }
    __syncthreads();
  }
  if (tid<4) s_red[0][tid]=priv;
  __syncthreads();
  if (tid==0) out[n]=(s_red[0][0]+s_red[0][1]+s_red[0][2]+s_red[0][3])*(1.0f/2000.0f);
}

extern "C" void kernel_launch(void* const* d_in, const int* in_sizes, int n_in,
                              void* d_out, int out_size, void* d_ws, size_t ws_size,
                              hipStream_t stream){
  (void)n_in; (void)out_size; (void)ws_size;
  const float* ev   = (const float*)d_in[0];
  const float* wig  = (const float*)d_in[1];
  const float* winv = (const float*)d_in[2];
  const float* spe  = (const float*)d_in[3];
  const float* ese  = (const float*)d_in[4];
  const float* degW1= (const float*)d_in[5];
  const float* degb1= (const float*)d_in[6];
  const float* degW2= (const float*)d_in[7];
  const float* degb2= (const float*)d_in[8];
  const float* n1w  = (const float*)d_in[9];
  const float* radW1= (const float*)d_in[10];
  const float* radb1= (const float*)d_in[11];
  const float* radW2= (const float*)d_in[12];
  const float* radb2= (const float*)d_in[13];
  const float* so2W = (const float*)d_in[14];
  const float* aW   = (const float*)d_in[15];
  const float* aV   = (const float*)d_in[16];
  const float* vW   = (const float*)d_in[17];
  const float* pW   = (const float*)d_in[18];
  const float* n2w  = (const float*)d_in[19];
  const float* fW1  = (const float*)d_in[20];
  const float* fb1  = (const float*)d_in[21];
  const float* fW2  = (const float*)d_in[22];
  const float* tg   = (const float*)d_in[23];
  const float* fg   = (const float*)d_in[24];
  const float* fnw  = (const float*)d_in[25];
  const float* enW1 = (const float*)d_in[26];
  const float* enb1 = (const float*)d_in[27];
  const float* enW2 = (const float*)d_in[28];
  const float* enb2 = (const float*)d_in[29];
  const int* nsp = (const int*)d_in[30];
  const int* snd = (const int*)d_in[31];
  const int* rcv = (const int*)d_in[32];
  int N = in_sizes[30];
  int E = in_sizes[31];
  float* out = (float*)d_out;

  float* ws = (float*)d_ws;
  size_t off = 0;
  float* radbuf = ws + off; off += (size_t)E*384;
  float* logits = ws + off; off += (size_t)E*8;
  float* mx     = ws + off; off += (size_t)N*8;
  float* den    = ws + off; off += (size_t)N*8;
  float* x      = ws + off; off += (size_t)N*1600;
  float* xn     = ws + off; off += (size_t)N*1600;
  unsigned short* wsvb  = (unsigned short*)(ws + off); off += (size_t)6*16384/2;
  unsigned short* projb = (unsigned short*)(ws + off); off += (size_t)6*8192/2;
  int* cnt      = (int*)(ws + off); off += (size_t)N;
  int* rowptr   = (int*)(ws + off); off += (size_t)(N+1);
  int* fill     = (int*)(ws + off); off += (size_t)N;
  int* eixbuf   = (int*)(ws + off); off += (size_t)E;

  // CSR by receiver + bf16 fused weights
  zero_cnt_kernel<<<(N+255)/256, 256, 0, stream>>>(cnt, N);
  csr_count_kernel<<<(E+255)/256, 256, 0, stream>>>(rcv, cnt, E);
  csr_scan_kernel<<<1, 256, 0, stream>>>(cnt, rowptr, fill, N);
  csr_fill_kernel<<<(E+255)/256, 256, 0, stream>>>(rcv, fill, eixbuf, E);
  wsvb_kernel<<<6, 256, 0, stream>>>(so2W, vW, wsvb);
  projb_kernel<<<6, 256, 0, stream>>>(pW, projb);

  deg_gather_kernel<<<N, 256, 0, stream>>>(ev, ese, nsp, spe, degW1, degb1, degW2, degb2,
                                           winv, snd, rowptr, eixbuf, x, N);

  for (int i=0;i<2;i++){
    rmsnorm_kernel<<<N, 256, 0, stream>>>(x, n1w + (size_t)i*320, xn, N);
    init_mxden_kernel<<<(N*8+255)/256, 256, 0, stream>>>(mx, den, N);
    rad_kernel<<<(E+3)/4, 256, 0, stream>>>(ev, ese, nsp, radW1 + (size_t)i*DIN*128, radb1 + (size_t)i*128,
                                            radW2 + (size_t)i*128*384, radb2 + (size_t)i*384,
                                            snd, rcv, radbuf, E);
    logits_kernel<<<E, 256, 0, stream>>>(xn, wig, radbuf, so2W + (size_t)i*24576,
                                         aW + (size_t)i*64*256, aV + (size_t)i*256,
                                         snd, rcv, logits, mx, E);
    den_kernel<<<(E*8+255)/256, 256, 0, stream>>>(logits, mx, rcv, den, E);
    attn_gather_kernel<<<N, 256, 0, stream>>>(xn, wig, winv, radbuf,
                                              wsvb + (size_t)i*3*16384, projb + (size_t)i*3*8192,
                                              logits, mx, den, snd, rowptr, eixbuf, x, N);
    rmsnorm_kernel<<<N, 256, 0, stream>>>(x, n2w + (size_t)i*320, xn, N);
    grid_ffn_kernel<<<N, 256, 0, stream>>>(xn, tg, fg, fW1 + (size_t)i*8192, fb1 + (size_t)i*128,
                                           fW2 + (size_t)i*8192, x, N);
  }
  rmsnorm_kernel<<<N, 256, 0, stream>>>(x, fnw, xn, N);
  energy_kernel<<<N, 256, 0, stream>>>(xn, tg, fg, enW1, enb1, enW2, enb2, out, N);
}